// Round 1
// baseline (1082.809 us; speedup 1.0000x reference)
//
#include <hip/hip_runtime.h>
#include <hip/hip_fp16.h>

#define HID   256
#define NHEAD 4
#define DOUT  64
#define ADIM  74
#define KPAD_IN 96
#define LAYERS 3

typedef _Float16 half8 __attribute__((ext_vector_type(8)));
typedef _Float16 half4 __attribute__((ext_vector_type(4)));
typedef float f32x4 __attribute__((ext_vector_type(4)));

// ---------------- weight prep: WT[n][k] = W[k][n] in f16 -------------------
__global__ void k_prep_wt(const float* __restrict__ Ws, const float* __restrict__ Wd,
                          _Float16* __restrict__ WT) {
  int id = blockIdx.x * 256 + threadIdx.x;   // 512*256
  if (id >= 512 * HID) return;
  int n = id >> 8, k = id & 255;
  float v = (n < HID) ? Ws[k * HID + n] : Wd[k * HID + (n - HID)];
  WT[id] = (_Float16)v;
}

__global__ void k_prep_win(const float* __restrict__ Win, _Float16* __restrict__ WT) {
  int id = blockIdx.x * 256 + threadIdx.x;   // 256*96
  if (id >= HID * KPAD_IN) return;
  int n = id / KPAD_IN, k = id % KPAD_IN;
  WT[id] = (_Float16)((k < ADIM) ? Win[k * HID + n] : 0.f);
}

// ---------------- GEMM: C[M][Ntot] = A[M][K](f32) @ WT^T, f16 MFMA ----------
// A fp32 [M][lda]; B = WT [Ntot][KPAD] f16 (k-major rows). 128x128 tile, BK=32.
__global__ __launch_bounds__(256)
void k_gemm(const float* __restrict__ A, int M, int K, int lda,
            const _Float16* __restrict__ B, int KPAD, int nsteps,
            const float* __restrict__ bias0, const float* __restrict__ bias1,
            int mode, float* __restrict__ outF,
            _Float16* __restrict__ outS, _Float16* __restrict__ outD)
{
  __shared__ _Float16 Ah[128][40];
  __shared__ _Float16 Bh[128][40];
  const int t = threadIdx.x;
  const int lane = t & 63, wid = t >> 6;
  const int wm = wid >> 1, wn = wid & 1;
  const int row0 = blockIdx.x * 128;
  const int col0 = blockIdx.y * 128;
  const bool vecA = ((lda & 3) == 0);

  f32x4 zero = {0.f, 0.f, 0.f, 0.f};
  f32x4 acc[4][4];
  for (int i = 0; i < 4; ++i) for (int j = 0; j < 4; ++j) acc[i][j] = zero;

  for (int kt = 0; kt < nsteps; ++kt) {
    const int kb = kt * 32;
    // stage A (128x32 f32 -> f16)
    #pragma unroll
    for (int it = 0; it < 4; ++it) {
      int idx = t + it * 256;            // 0..1023
      int r = idx >> 3, c4 = idx & 7;
      int gr = row0 + r;
      int k0 = kb + c4 * 4;
      float x0 = 0.f, x1 = 0.f, x2 = 0.f, x3 = 0.f;
      if (gr < M) {
        if (vecA && (k0 + 3 < K)) {
          float4 v = *(const float4*)(A + (size_t)gr * lda + k0);
          x0 = v.x; x1 = v.y; x2 = v.z; x3 = v.w;
        } else {
          const float* ap = A + (size_t)gr * lda;
          if (k0 + 0 < K) x0 = ap[k0 + 0];
          if (k0 + 1 < K) x1 = ap[k0 + 1];
          if (k0 + 2 < K) x2 = ap[k0 + 2];
          if (k0 + 3 < K) x3 = ap[k0 + 3];
        }
      }
      _Float16* dp = &Ah[r][c4 * 4];
      dp[0] = (_Float16)x0; dp[1] = (_Float16)x1; dp[2] = (_Float16)x2; dp[3] = (_Float16)x3;
    }
    // stage B (128 rows x 32 f16 = 64B/row)
    #pragma unroll
    for (int it = 0; it < 2; ++it) {
      int idx = t + it * 256;            // 0..511
      int r = idx >> 2, c = idx & 3;
      uint4 v = *(const uint4*)(B + (size_t)(col0 + r) * KPAD + kb + c * 8);
      *(uint4*)&Bh[r][c * 8] = v;
    }
    __syncthreads();
    half8 af[4], bf[4];
    #pragma unroll
    for (int i = 0; i < 4; ++i)
      af[i] = *(half8*)&Ah[wm * 64 + i * 16 + (lane & 15)][(lane >> 4) * 8];
    #pragma unroll
    for (int j = 0; j < 4; ++j)
      bf[j] = *(half8*)&Bh[wn * 64 + j * 16 + (lane & 15)][(lane >> 4) * 8];
    #pragma unroll
    for (int i = 0; i < 4; ++i)
      #pragma unroll
      for (int j = 0; j < 4; ++j)
        acc[i][j] = __builtin_amdgcn_mfma_f32_16x16x32_f16(af[i], bf[j], acc[i][j], 0, 0, 0);
    __syncthreads();
  }
  // epilogue
  const int rbase = row0 + wm * 64;
  const int cbase = col0 + wn * 64;
  #pragma unroll
  for (int i = 0; i < 4; ++i) {
    #pragma unroll
    for (int j = 0; j < 4; ++j) {
      int col = cbase + j * 16 + (lane & 15);
      float bv = (col < HID) ? bias0[col] : bias1[col - HID];
      #pragma unroll
      for (int r = 0; r < 4; ++r) {
        int row = rbase + i * 16 + (lane >> 4) * 4 + r;
        if (row < M) {
          float val = acc[i][j][r] + bv;
          if (mode == 0) {
            outF[(size_t)row * HID + col] = val;
          } else {
            if (col < HID) outS[(size_t)row * HID + col] = (_Float16)val;
            else           outD[(size_t)row * HID + col - HID] = (_Float16)val;
          }
        }
      }
    }
  }
}

// ---------------- edge kernels --------------------------------------------
__global__ __launch_bounds__(256)
void k_logits(const int* __restrict__ src, const int* __restrict__ dst,
              const _Float16* __restrict__ fs, const _Float16* __restrict__ fd,
              const float* __restrict__ attn, float* __restrict__ lg,
              int* __restrict__ mkey, int E)
{
  int wid = threadIdx.x >> 6;
  int e = blockIdx.x * 4 + wid;
  if (e >= E) return;
  int lane = threadIdx.x & 63;
  int s = src[e], d = dst[e];
  int j0 = lane * 4;
  int h = lane >> 4;
  half4 a = *(const half4*)&fs[(size_t)s * HID + j0];
  half4 b = *(const half4*)&fd[(size_t)d * HID + j0];
  float4 av = *(const float4*)&attn[h * DOUT + (lane & 15) * 4];
  const float* avp = (const float*)&av;
  float p = 0.f;
  #pragma unroll
  for (int q = 0; q < 4; ++q) {
    float x = (float)a[q] + (float)b[q];
    x = x > 0.f ? x : 0.2f * x;
    p += x * avp[q];
  }
  p += __shfl_xor(p, 1);
  p += __shfl_xor(p, 2);
  p += __shfl_xor(p, 4);
  p += __shfl_xor(p, 8);
  if ((lane & 15) == 0) {
    lg[e * 4 + h] = p;
    int ib = __float_as_int(p);
    int key = ib < 0 ? (ib ^ 0x7FFFFFFF) : ib;
    atomicMax(&mkey[d * 4 + h], key);
  }
}

__global__ void k_expsum(const int* __restrict__ dst, const int* __restrict__ mkey,
                         float* __restrict__ lg, float* __restrict__ denom, int E)
{
  int i = blockIdx.x * 256 + threadIdx.x;
  if (i >= E * NHEAD) return;
  int e = i >> 2, h = i & 3;
  int d = dst[e];
  int key = mkey[d * 4 + h];
  float m = __int_as_float(key < 0 ? (key ^ 0x7FFFFFFF) : key);
  float ex = __expf(lg[i] - m);
  lg[i] = ex;
  atomicAdd(&denom[d * 4 + h], ex);
}

__global__ __launch_bounds__(256)
void k_aggregate(const int* __restrict__ src, const int* __restrict__ offs,
                 const int* __restrict__ eids, const float* __restrict__ ex,
                 const float* __restrict__ denom, const _Float16* __restrict__ fs,
                 const float* __restrict__ bias, float* __restrict__ hout, int N)
{
  int wid = threadIdx.x >> 6;
  int n = blockIdx.x * 4 + wid;
  if (n >= N) return;
  int lane = threadIdx.x & 63;
  int h = lane >> 4, j0 = lane * 4;
  int t0 = offs[n], t1 = offs[n + 1];
  float dn = denom[n * 4 + h];
  float inv = (t1 > t0) ? (1.0f / dn) : 0.f;
  float a0 = 0.f, a1 = 0.f, a2 = 0.f, a3 = 0.f;
  for (int tt = t0; tt < t1; ++tt) {
    int eid = eids[tt];
    float alpha = ex[eid * 4 + h] * inv;
    half4 v = *(const half4*)&fs[(size_t)src[eid] * HID + j0];
    a0 += alpha * (float)v[0];
    a1 += alpha * (float)v[1];
    a2 += alpha * (float)v[2];
    a3 += alpha * (float)v[3];
  }
  float4 o;
  o.x = a0 + bias[j0 + 0];
  o.y = a1 + bias[j0 + 1];
  o.z = a2 + bias[j0 + 2];
  o.w = a3 + bias[j0 + 3];
  *(float4*)&hout[(size_t)n * HID + j0] = o;
}

// ---------------- CSR build ------------------------------------------------
__global__ void k_zero_i(int* p, int n) {
  int i = blockIdx.x * 256 + threadIdx.x;
  if (i < n) p[i] = 0;
}
__global__ void k_init_md(int* mkey, float* denom, int n4) {
  int i = blockIdx.x * 256 + threadIdx.x;
  if (i < n4) { mkey[i] = (int)0x80000000; denom[i] = 0.f; }
}
__global__ void k_count(const int* __restrict__ dst, int* __restrict__ counts, int E) {
  int i = blockIdx.x * 256 + threadIdx.x;
  if (i < E) atomicAdd(&counts[dst[i]], 1);
}
__global__ __launch_bounds__(1024)
void k_scan1(const int* __restrict__ counts, int* __restrict__ offs,
             int* __restrict__ bsums, int N)
{
  __shared__ int sd[1024];
  int t = threadIdx.x, i = blockIdx.x * 1024 + t;
  int x = (i < N) ? counts[i] : 0;
  sd[t] = x;
  __syncthreads();
  for (int off = 1; off < 1024; off <<= 1) {
    int v = (t >= off) ? sd[t - off] : 0;
    __syncthreads();
    sd[t] += v;
    __syncthreads();
  }
  if (i < N) offs[i] = sd[t] - x;
  if (t == 0) bsums[blockIdx.x] = sd[1023];
}
__global__ void k_scan2(const int* __restrict__ bsums, int* __restrict__ boffs,
                        int* __restrict__ offs, int nb, int N)
{
  if (threadIdx.x == 0 && blockIdx.x == 0) {
    int run = 0;
    for (int b = 0; b < nb; ++b) { boffs[b] = run; run += bsums[b]; }
    offs[N] = run;
  }
}
__global__ __launch_bounds__(1024)
void k_scan3(const int* __restrict__ boffs, int* __restrict__ offs,
             int* __restrict__ cursor, int N)
{
  int i = blockIdx.x * 1024 + threadIdx.x;
  if (i < N) {
    int v = offs[i] + boffs[blockIdx.x];
    offs[i] = v;
    cursor[i] = v;
  }
}
__global__ void k_scatter(const int* __restrict__ dst, int* __restrict__ cursor,
                          int* __restrict__ eids, int E)
{
  int i = blockIdx.x * 256 + threadIdx.x;
  if (i < E) {
    int pos = atomicAdd(&cursor[dst[i]], 1);
    eids[pos] = i;
  }
}

// ---------------- launch ---------------------------------------------------
extern "C" void kernel_launch(void* const* d_in, const int* in_sizes, int n_in,
                              void* d_out, int out_size, void* d_ws, size_t ws_size,
                              hipStream_t stream)
{
  const float* atom  = (const float*)d_in[0];
  const int*   src   = (const int*)d_in[1];
  const int*   dst   = (const int*)d_in[2];
  const float* W_in  = (const float*)d_in[3];
  const float* b_in  = (const float*)d_in[4];
  const float* W_src = (const float*)d_in[5];
  const float* b_src = (const float*)d_in[6];
  const float* W_dst = (const float*)d_in[7];
  const float* b_dst = (const float*)d_in[8];
  const float* attn  = (const float*)d_in[9];
  const float* bias  = (const float*)d_in[10];

  const int N = in_sizes[0] / ADIM;
  const int E = in_sizes[1];
  float* h = (float*)d_out;   // h buffer lives in d_out (N*256 f32), rewritten fully

  // workspace carve (256B aligned)
  char* w = (char*)d_ws;
  size_t off = 0;
  auto carve = [&](size_t bytes) {
    void* p = w + off;
    off = (off + bytes + 255) & ~(size_t)255;
    return p;
  };
  _Float16* fs    = (_Float16*)carve((size_t)N * HID * 2);
  _Float16* fd    = (_Float16*)carve((size_t)N * HID * 2);
  float*    lg    = (float*)carve((size_t)E * NHEAD * 4);
  int*      mkey  = (int*)carve((size_t)N * NHEAD * 4);
  float*    denom = (float*)carve((size_t)N * NHEAD * 4);
  _Float16* WT    = (_Float16*)carve((size_t)512 * HID * 2);
  _Float16* WTin  = (_Float16*)carve((size_t)HID * KPAD_IN * 2);
  int*      counts= (int*)carve((size_t)N * 4);
  int*      offs  = (int*)carve((size_t)(N + 1) * 4);
  int*      cursor= (int*)carve((size_t)N * 4);
  int*      eids  = (int*)carve((size_t)E * 4);
  int*      bsums = (int*)carve((size_t)1024 * 4);
  int*      boffs = (int*)carve((size_t)1024 * 4);
  (void)ws_size; (void)n_in; (void)out_size;

  const int nb = (N + 1023) / 1024;
  const int gmx = (N + 127) / 128;

  // input projection weights + h0
  k_prep_win<<<(HID * KPAD_IN + 255) / 256, 256, 0, stream>>>(W_in, WTin);
  k_gemm<<<dim3(gmx, 2), 256, 0, stream>>>(atom, N, ADIM, ADIM, WTin, KPAD_IN, KPAD_IN / 32,
                                           b_in, b_in, 0, h, nullptr, nullptr);

  // CSR by dst (layer-invariant)
  k_zero_i<<<(N + 255) / 256, 256, 0, stream>>>(counts, N);
  k_count<<<(E + 255) / 256, 256, 0, stream>>>(dst, counts, E);
  k_scan1<<<nb, 1024, 0, stream>>>(counts, offs, bsums, N);
  k_scan2<<<1, 64, 0, stream>>>(bsums, boffs, offs, nb, N);
  k_scan3<<<nb, 1024, 0, stream>>>(boffs, offs, cursor, N);
  k_scatter<<<(E + 255) / 256, 256, 0, stream>>>(dst, cursor, eids, E);

  for (int l = 0; l < LAYERS; ++l) {
    k_prep_wt<<<(512 * HID + 255) / 256, 256, 0, stream>>>(W_src + (size_t)l * HID * HID,
                                                           W_dst + (size_t)l * HID * HID, WT);
    k_gemm<<<dim3(gmx, 4), 256, 0, stream>>>(h, N, HID, HID, WT, HID, HID / 32,
                                             b_src + (size_t)l * HID, b_dst + (size_t)l * HID,
                                             1, nullptr, fs, fd);
    k_init_md<<<(N * NHEAD + 255) / 256, 256, 0, stream>>>(mkey, denom, N * NHEAD);
    k_logits<<<(E + 3) / 4, 256, 0, stream>>>(src, dst, fs, fd, attn + (size_t)l * NHEAD * DOUT,
                                              lg, mkey, E);
    k_expsum<<<(E * NHEAD + 255) / 256, 256, 0, stream>>>(dst, mkey, lg, denom, E);
    k_aggregate<<<(N + 3) / 4, 256, 0, stream>>>(src, offs, eids, lg, denom, fs,
                                                 bias + (size_t)l * HID, h, N);
  }
}

// Round 2
// 598.597 us; speedup vs baseline: 1.8089x; 1.8089x over previous
//
#include <hip/hip_runtime.h>
#include <hip/hip_fp16.h>

#define HID   256
#define NHEAD 4
#define DOUT  64
#define ADIM  74
#define KPAD_IN 96
#define LAYERS 3

typedef _Float16 half8 __attribute__((ext_vector_type(8)));
typedef _Float16 half4 __attribute__((ext_vector_type(4)));
typedef float f32x4 __attribute__((ext_vector_type(4)));

// ---------------- weight prep: WT[n][k] = W[k][n] in f16 -------------------
__global__ void k_prep_wt(const float* __restrict__ Ws, const float* __restrict__ Wd,
                          _Float16* __restrict__ WT) {
  int id = blockIdx.x * 256 + threadIdx.x;   // 512*256
  if (id >= 512 * HID) return;
  int n = id >> 8, k = id & 255;
  float v = (n < HID) ? Ws[k * HID + n] : Wd[k * HID + (n - HID)];
  WT[id] = (_Float16)v;
}

__global__ void k_prep_win(const float* __restrict__ Win, _Float16* __restrict__ WT) {
  int id = blockIdx.x * 256 + threadIdx.x;   // 256*96
  if (id >= HID * KPAD_IN) return;
  int n = id / KPAD_IN, k = id % KPAD_IN;
  WT[id] = (_Float16)((k < ADIM) ? Win[k * HID + n] : 0.f);
}

// ---------------- GEMM: C[M][Ntot] = A @ WT^T, f16 MFMA --------------------
// A: fp16 [M][lda] (AHALF) or fp32 [M][lda]; B = WT [Ntot][KPAD] f16.
// Grid: (ncol, nrow) -- column fastest for A-panel L2/L3 reuse.
// Output always f16: col<HID -> outS, else outD (col-HID).
template<bool AHALF>
__global__ __launch_bounds__(256)
void k_gemm(const void* __restrict__ Av, int M, int K, int lda,
            const _Float16* __restrict__ B, int KPAD, int nsteps,
            const float* __restrict__ bias0, const float* __restrict__ bias1,
            _Float16* __restrict__ outS, _Float16* __restrict__ outD)
{
  __shared__ _Float16 Ah[128][40];
  __shared__ _Float16 Bh[128][40];
  const int t = threadIdx.x;
  const int lane = t & 63, wid = t >> 6;
  const int wm = wid >> 1, wn = wid & 1;
  const int col0 = blockIdx.x * 128;
  const int row0 = blockIdx.y * 128;

  f32x4 zero = {0.f, 0.f, 0.f, 0.f};
  f32x4 acc[4][4];
  for (int i = 0; i < 4; ++i) for (int j = 0; j < 4; ++j) acc[i][j] = zero;

  for (int kt = 0; kt < nsteps; ++kt) {
    const int kb = kt * 32;
    // stage A (128 rows x 32 f16 = 64B/row)
    if (AHALF) {
      const _Float16* A = (const _Float16*)Av;
      #pragma unroll
      for (int it = 0; it < 2; ++it) {
        int idx = t + it * 256;           // 0..511
        int r = idx >> 2, c = idx & 3;
        int gr = row0 + r;
        uint4 v = {0u, 0u, 0u, 0u};
        if (gr < M) v = *(const uint4*)(A + (size_t)gr * lda + kb + c * 8);
        *(uint2*)&Ah[r][c * 8]     = make_uint2(v.x, v.y);
        *(uint2*)&Ah[r][c * 8 + 4] = make_uint2(v.z, v.w);
      }
    } else {
      const float* A = (const float*)Av;
      #pragma unroll
      for (int it = 0; it < 4; ++it) {
        int idx = t + it * 256;           // 0..1023
        int r = idx >> 3, c4 = idx & 7;
        int gr = row0 + r;
        int k0 = kb + c4 * 4;
        float x0 = 0.f, x1 = 0.f, x2 = 0.f, x3 = 0.f;
        if (gr < M) {
          const float* ap = A + (size_t)gr * lda;
          if (k0 + 0 < K) x0 = ap[k0 + 0];
          if (k0 + 1 < K) x1 = ap[k0 + 1];
          if (k0 + 2 < K) x2 = ap[k0 + 2];
          if (k0 + 3 < K) x3 = ap[k0 + 3];
        }
        _Float16* dp = &Ah[r][c4 * 4];
        dp[0] = (_Float16)x0; dp[1] = (_Float16)x1; dp[2] = (_Float16)x2; dp[3] = (_Float16)x3;
      }
    }
    // stage B (128 rows x 32 f16)
    #pragma unroll
    for (int it = 0; it < 2; ++it) {
      int idx = t + it * 256;             // 0..511
      int r = idx >> 2, c = idx & 3;
      uint4 v = *(const uint4*)(B + (size_t)(col0 + r) * KPAD + kb + c * 8);
      *(uint2*)&Bh[r][c * 8]     = make_uint2(v.x, v.y);
      *(uint2*)&Bh[r][c * 8 + 4] = make_uint2(v.z, v.w);
    }
    __syncthreads();
    half8 af[4], bf[4];
    #pragma unroll
    for (int i = 0; i < 4; ++i)
      af[i] = *(half8*)&Ah[wm * 64 + i * 16 + (lane & 15)][(lane >> 4) * 8];
    #pragma unroll
    for (int j = 0; j < 4; ++j)
      bf[j] = *(half8*)&Bh[wn * 64 + j * 16 + (lane & 15)][(lane >> 4) * 8];
    #pragma unroll
    for (int i = 0; i < 4; ++i)
      #pragma unroll
      for (int j = 0; j < 4; ++j)
        acc[i][j] = __builtin_amdgcn_mfma_f32_16x16x32_f16(af[i], bf[j], acc[i][j], 0, 0, 0);
    __syncthreads();
  }
  // epilogue (f16 out + bias)
  const int rbase = row0 + wm * 64;
  const int cbase = col0 + wn * 64;
  #pragma unroll
  for (int i = 0; i < 4; ++i) {
    #pragma unroll
    for (int j = 0; j < 4; ++j) {
      int col = cbase + j * 16 + (lane & 15);
      float bv = (col < HID) ? bias0[col] : bias1[col - HID];
      #pragma unroll
      for (int r = 0; r < 4; ++r) {
        int row = rbase + i * 16 + (lane >> 4) * 4 + r;
        if (row < M) {
          float val = acc[i][j][r] + bv;
          if (col < HID) outS[(size_t)row * HID + col] = (_Float16)val;
          else           outD[(size_t)row * HID + col - HID] = (_Float16)val;
        }
      }
    }
  }
}

// ------------- fused edge phase: online segment-softmax + aggregate --------
// One wave per dst node. CSR order (esrc pre-permuted). Flash-style online
// softmax per head; acc over the lane's 4 dims. No atomics, single fs gather.
__global__ __launch_bounds__(256)
void k_fused(const int* __restrict__ offs, const int* __restrict__ esrc,
             const _Float16* __restrict__ fs, const _Float16* __restrict__ fd,
             const float* __restrict__ attn, const float* __restrict__ bias,
             _Float16* __restrict__ hhalf, float* __restrict__ hfloat, int N)
{
  int wid = threadIdx.x >> 6;
  int n = blockIdx.x * 4 + wid;
  if (n >= N) return;
  int lane = threadIdx.x & 63;
  int h = lane >> 4;
  int j0 = lane * 4;
  half4 fdv = *(const half4*)&fd[(size_t)n * HID + j0];
  float4 av = *(const float4*)&attn[h * DOUT + (lane & 15) * 4];
  float4 bv = *(const float4*)&bias[j0];
  int t0 = offs[n], t1 = offs[n + 1];
  float m = -1e30f, ssum = 0.f;
  float a0 = 0.f, a1 = 0.f, a2 = 0.f, a3 = 0.f;
  for (int tt = t0; tt < t1; ++tt) {
    int s = esrc[tt];
    half4 fsv = *(const half4*)&fs[(size_t)s * HID + j0];
    float f0 = (float)fsv[0], f1 = (float)fsv[1], f2 = (float)fsv[2], f3 = (float)fsv[3];
    float x, p = 0.f;
    x = f0 + (float)fdv[0]; x = x > 0.f ? x : 0.2f * x; p += x * av.x;
    x = f1 + (float)fdv[1]; x = x > 0.f ? x : 0.2f * x; p += x * av.y;
    x = f2 + (float)fdv[2]; x = x > 0.f ? x : 0.2f * x; p += x * av.z;
    x = f3 + (float)fdv[3]; x = x > 0.f ? x : 0.2f * x; p += x * av.w;
    p += __shfl_xor(p, 1);
    p += __shfl_xor(p, 2);
    p += __shfl_xor(p, 4);
    p += __shfl_xor(p, 8);          // all 16 lanes of this head hold the logit
    float mn = fmaxf(m, p);
    float scale = __expf(m - mn);
    float w = __expf(p - mn);
    ssum = ssum * scale + w;
    a0 = a0 * scale + w * f0;
    a1 = a1 * scale + w * f1;
    a2 = a2 * scale + w * f2;
    a3 = a3 * scale + w * f3;
    m = mn;
  }
  float inv = (t1 > t0) ? 1.0f / ssum : 0.f;
  float o0 = a0 * inv + bv.x;
  float o1 = a1 * inv + bv.y;
  float o2 = a2 * inv + bv.z;
  float o3 = a3 * inv + bv.w;
  if (hhalf) {
    half4 hv = {(_Float16)o0, (_Float16)o1, (_Float16)o2, (_Float16)o3};
    *(half4*)&hhalf[(size_t)n * HID + j0] = hv;
  }
  if (hfloat) {
    float4 ov = {o0, o1, o2, o3};
    *(float4*)&hfloat[(size_t)n * HID + j0] = ov;
  }
}

// ---------------- CSR build ------------------------------------------------
__global__ void k_zero_i(int* p, int n) {
  int i = blockIdx.x * 256 + threadIdx.x;
  if (i < n) p[i] = 0;
}
__global__ void k_count(const int* __restrict__ dst, int* __restrict__ counts, int E) {
  int i = blockIdx.x * 256 + threadIdx.x;
  if (i < E) atomicAdd(&counts[dst[i]], 1);
}
__global__ __launch_bounds__(1024)
void k_scan1(const int* __restrict__ counts, int* __restrict__ offs,
             int* __restrict__ bsums, int N)
{
  __shared__ int sd[1024];
  int t = threadIdx.x, i = blockIdx.x * 1024 + t;
  int x = (i < N) ? counts[i] : 0;
  sd[t] = x;
  __syncthreads();
  for (int off = 1; off < 1024; off <<= 1) {
    int v = (t >= off) ? sd[t - off] : 0;
    __syncthreads();
    sd[t] += v;
    __syncthreads();
  }
  if (i < N) offs[i] = sd[t] - x;
  if (t == 0) bsums[blockIdx.x] = sd[1023];
}
__global__ void k_scan2(const int* __restrict__ bsums, int* __restrict__ boffs,
                        int* __restrict__ offs, int nb, int N)
{
  if (threadIdx.x == 0 && blockIdx.x == 0) {
    int run = 0;
    for (int b = 0; b < nb; ++b) { boffs[b] = run; run += bsums[b]; }
    offs[N] = run;
  }
}
__global__ __launch_bounds__(1024)
void k_scan3(const int* __restrict__ boffs, int* __restrict__ offs,
             int* __restrict__ cursor, int N)
{
  int i = blockIdx.x * 1024 + threadIdx.x;
  if (i < N) {
    int v = offs[i] + boffs[blockIdx.x];
    offs[i] = v;
    cursor[i] = v;
  }
}
__global__ void k_scatter(const int* __restrict__ src, const int* __restrict__ dst,
                          int* __restrict__ cursor, int* __restrict__ esrc, int E)
{
  int i = blockIdx.x * 256 + threadIdx.x;
  if (i < E) {
    int pos = atomicAdd(&cursor[dst[i]], 1);
    esrc[pos] = src[i];
  }
}

// ---------------- launch ---------------------------------------------------
extern "C" void kernel_launch(void* const* d_in, const int* in_sizes, int n_in,
                              void* d_out, int out_size, void* d_ws, size_t ws_size,
                              hipStream_t stream)
{
  const float* atom  = (const float*)d_in[0];
  const int*   src   = (const int*)d_in[1];
  const int*   dst   = (const int*)d_in[2];
  const float* W_in  = (const float*)d_in[3];
  const float* b_in  = (const float*)d_in[4];
  const float* W_src = (const float*)d_in[5];
  const float* b_src = (const float*)d_in[6];
  const float* W_dst = (const float*)d_in[7];
  const float* b_dst = (const float*)d_in[8];
  const float* attn  = (const float*)d_in[9];
  const float* bias  = (const float*)d_in[10];

  const int N = in_sizes[0] / ADIM;
  const int E = in_sizes[1];
  // h (fp16, intermediate) aliases the front of d_out; the last layer's fused
  // kernel fully rewrites d_out as fp32 AFTER the last GEMM consumed h_half.
  _Float16* h_half = (_Float16*)d_out;
  float*    h_out  = (float*)d_out;

  char* w = (char*)d_ws;
  size_t off = 0;
  auto carve = [&](size_t bytes) {
    void* p = w + off;
    off = (off + bytes + 255) & ~(size_t)255;
    return p;
  };
  _Float16* fs    = (_Float16*)carve((size_t)N * HID * 2);
  _Float16* fd    = (_Float16*)carve((size_t)N * HID * 2);
  _Float16* WT    = (_Float16*)carve((size_t)512 * HID * 2);
  _Float16* WTin  = (_Float16*)carve((size_t)HID * KPAD_IN * 2);
  int*      counts= (int*)carve((size_t)N * 4);
  int*      offs  = (int*)carve((size_t)(N + 1) * 4);
  int*      cursor= (int*)carve((size_t)N * 4);
  int*      esrc  = (int*)carve((size_t)E * 4);
  int*      bsums = (int*)carve((size_t)1024 * 4);
  int*      boffs = (int*)carve((size_t)1024 * 4);
  (void)ws_size; (void)n_in; (void)out_size;

  const int nb = (N + 1023) / 1024;
  const int gmx = (N + 127) / 128;

  // CSR by dst (layer-invariant)
  k_zero_i<<<(N + 255) / 256, 256, 0, stream>>>(counts, N);
  k_count<<<(E + 255) / 256, 256, 0, stream>>>(dst, counts, E);
  k_scan1<<<nb, 1024, 0, stream>>>(counts, offs, bsums, N);
  k_scan2<<<1, 64, 0, stream>>>(bsums, boffs, offs, nb, N);
  k_scan3<<<nb, 1024, 0, stream>>>(boffs, offs, cursor, N);
  k_scatter<<<(E + 255) / 256, 256, 0, stream>>>(src, dst, cursor, esrc, E);

  // input projection -> h_half (fp16)
  k_prep_win<<<(HID * KPAD_IN + 255) / 256, 256, 0, stream>>>(W_in, WTin);
  k_gemm<false><<<dim3(2, gmx), 256, 0, stream>>>(atom, N, ADIM, ADIM, WTin, KPAD_IN,
                                                  KPAD_IN / 32, b_in, b_in, h_half, h_half);

  for (int l = 0; l < LAYERS; ++l) {
    k_prep_wt<<<(512 * HID + 255) / 256, 256, 0, stream>>>(W_src + (size_t)l * HID * HID,
                                                           W_dst + (size_t)l * HID * HID, WT);
    k_gemm<true><<<dim3(4, gmx), 256, 0, stream>>>(h_half, N, HID, HID, WT, HID, HID / 32,
                                                   b_src + (size_t)l * HID,
                                                   b_dst + (size_t)l * HID, fs, fd);
    const bool last = (l == LAYERS - 1);
    k_fused<<<(N + 3) / 4, 256, 0, stream>>>(offs, esrc, fs, fd,
                                             attn + (size_t)l * NHEAD * DOUT,
                                             bias + (size_t)l * HID,
                                             last ? nullptr : h_half,
                                             last ? h_out : nullptr, N);
  }
}

// Round 3
// 508.694 us; speedup vs baseline: 2.1286x; 1.1767x over previous
//
#include <hip/hip_runtime.h>
#include <hip/hip_fp16.h>

#define HID   256
#define NHEAD 4
#define DOUT  64
#define ADIM  74
#define KPAD_IN 96
#define LAYERS 3

typedef _Float16 half8 __attribute__((ext_vector_type(8)));
typedef _Float16 half4 __attribute__((ext_vector_type(4)));
typedef float f32x4 __attribute__((ext_vector_type(4)));

__device__ __forceinline__ void gload16(const void* g, void* l) {
  __builtin_amdgcn_global_load_lds((const __attribute__((address_space(1))) void*)g,
                                   (__attribute__((address_space(3))) void*)l, 16, 0, 0);
}

// ---------------- weight prep: WT[n][k] = W[k][n] in f16 -------------------
__global__ void k_prep_wt(const float* __restrict__ Ws, const float* __restrict__ Wd,
                          _Float16* __restrict__ WT) {
  int id = blockIdx.x * 256 + threadIdx.x;   // 512*256
  if (id >= 512 * HID) return;
  int n = id >> 8, k = id & 255;
  float v = (n < HID) ? Ws[k * HID + n] : Wd[k * HID + (n - HID)];
  WT[id] = (_Float16)v;
}

__global__ void k_prep_win(const float* __restrict__ Win, _Float16* __restrict__ WT) {
  int id = blockIdx.x * 256 + threadIdx.x;   // 256*96
  if (id >= HID * KPAD_IN) return;
  int n = id / KPAD_IN, k = id % KPAD_IN;
  WT[id] = (_Float16)((k < ADIM) ? Win[k * HID + n] : 0.f);
}

// ---- shared epilogue: acc(4x4 frags/wave) -> LDS f16 [128][136] -> stores --
__device__ __forceinline__ void gemm_epilogue(
    f32x4 acc[4][4], char* smem, int t, int lane, int wm, int wn,
    int row0, int col0, int M,
    const float* bias0, const float* bias1,
    _Float16* outS, _Float16* outD)
{
  const float* bp = (col0 < HID) ? (bias0 + col0) : (bias1 + (col0 - HID));
  _Float16*    op = (col0 < HID) ? (outS + col0) : (outD + (col0 - HID));
  _Float16 (*C)[136] = (_Float16(*)[136])smem;
  #pragma unroll
  for (int i = 0; i < 4; ++i) {
    #pragma unroll
    for (int j = 0; j < 4; ++j) {
      int lc = wn * 64 + j * 16 + (lane & 15);
      float bv = bp[lc];
      #pragma unroll
      for (int r = 0; r < 4; ++r) {
        int lr = wm * 64 + i * 16 + (lane >> 4) * 4 + r;
        C[lr][lc] = (_Float16)(acc[i][j][r] + bv);
      }
    }
  }
  __syncthreads();
  int lr = t >> 1, hf = t & 1;
  int grow = row0 + lr;
  if (grow < M) {
    _Float16* dst = op + (size_t)grow * HID + hf * 64;
    const _Float16* sp = &C[lr][hf * 64];
    #pragma unroll
    for (int q = 0; q < 8; ++q)
      *(uint4*)(dst + q * 8) = *(const uint4*)(sp + q * 8);
  }
}

// ------------- layer GEMM: C[M][512] = A(f16)[M][256] @ WT^T ---------------
// BK=64, 4 K-steps, global_load_lds + XOR-swizzle, 2-phase double-buffer.
__global__ __launch_bounds__(256)
void k_gemm_h(const _Float16* __restrict__ A, int M,
              const _Float16* __restrict__ B,
              const float* __restrict__ bias0, const float* __restrict__ bias1,
              _Float16* __restrict__ outS, _Float16* __restrict__ outD)
{
  __shared__ __align__(16) char smem[65536];   // 2 bufs x (A 16K | B 16K)
  const int t = threadIdx.x, lane = t & 63, wid = t >> 6;
  const int wm = wid >> 1, wn = wid & 1;
  const int col0 = blockIdx.x * 128, row0 = blockIdx.y * 128;

  f32x4 acc[4][4];
  #pragma unroll
  for (int i = 0; i < 4; ++i)
    #pragma unroll
    for (int j = 0; j < 4; ++j)
      acc[i][j] = (f32x4){0.f, 0.f, 0.f, 0.f};

  auto stage = [&](int kt, int buf) {
    const int kb = kt * 64;
    char* Ab = smem + buf * 32768;
    char* Bb = Ab + 16384;
    #pragma unroll
    for (int q = 0; q < 4; ++q) {
      int ci = wid * 4 + q;                 // 0..15, 1KB chunk (8 rows)
      int r = ci * 8 + (lane >> 3);
      int slot = (lane & 7) ^ (r & 7);      // inverse-swizzled source
      int grow = row0 + r; grow = grow < M ? grow : (M - 1);
      gload16(A + (size_t)grow * HID + kb + slot * 8, Ab + ci * 1024);
      gload16(B + (size_t)(col0 + r) * HID + kb + slot * 8, Bb + ci * 1024);
    }
  };

  stage(0, 0);
  __syncthreads();
  int cur = 0;
  for (int kt = 0; kt < 4; ++kt) {
    if (kt < 3) stage(kt + 1, cur ^ 1);
    const char* Ab = smem + cur * 32768;
    const char* Bb = Ab + 16384;
    #pragma unroll
    for (int kc = 0; kc < 2; ++kc) {
      half8 af[4], bf[4];
      #pragma unroll
      for (int i = 0; i < 4; ++i) {
        int r = wm * 64 + i * 16 + (lane & 15);
        int slot = (kc * 4 + (lane >> 4)) ^ (r & 7);
        af[i] = *(const half8*)(Ab + r * 128 + slot * 16);
      }
      #pragma unroll
      for (int j = 0; j < 4; ++j) {
        int r = wn * 64 + j * 16 + (lane & 15);
        int slot = (kc * 4 + (lane >> 4)) ^ (r & 7);
        bf[j] = *(const half8*)(Bb + r * 128 + slot * 16);
      }
      #pragma unroll
      for (int i = 0; i < 4; ++i)
        #pragma unroll
        for (int j = 0; j < 4; ++j)
          acc[i][j] = __builtin_amdgcn_mfma_f32_16x16x32_f16(af[i], bf[j], acc[i][j], 0, 0, 0);
    }
    __syncthreads();
    cur ^= 1;
  }
  gemm_epilogue(acc, smem, t, lane, wm, wn, row0, col0, M, bias0, bias1, outS, outD);
}

// ------------- input GEMM: C[M][256] = atom(f32)[M][74] @ WTin^T -----------
// BK=32, 3 K-steps (zero-padded), manual swizzled A stage, gload B.
__global__ __launch_bounds__(256)
void k_gemm_f(const float* __restrict__ A, int M,
              const _Float16* __restrict__ B,
              const float* __restrict__ bias0,
              _Float16* __restrict__ outS)
{
  __shared__ __align__(16) char smem[34816];   // A 8K | B 8K; epilogue 34816
  const int t = threadIdx.x, lane = t & 63, wid = t >> 6;
  const int wm = wid >> 1, wn = wid & 1;
  const int col0 = blockIdx.x * 128, row0 = blockIdx.y * 128;
  char* Ab = smem;
  char* Bb = smem + 8192;

  f32x4 acc[4][4];
  #pragma unroll
  for (int i = 0; i < 4; ++i)
    #pragma unroll
    for (int j = 0; j < 4; ++j)
      acc[i][j] = (f32x4){0.f, 0.f, 0.f, 0.f};

  for (int kt = 0; kt < 3; ++kt) {
    const int kb = kt * 32;
    // A: 128 rows x 32 f32 -> f16, swizzled LDS write (8B granules)
    #pragma unroll
    for (int it = 0; it < 4; ++it) {
      int idx = t + it * 256;               // 0..1023
      int r = idx >> 3, c4 = idx & 7;
      int gr = row0 + r;
      int k0 = kb + c4 * 4;
      float x0 = 0.f, x1 = 0.f, x2 = 0.f, x3 = 0.f;
      if (gr < M) {
        const float* ap = A + (size_t)gr * ADIM;
        if (k0 + 0 < ADIM) x0 = ap[k0 + 0];
        if (k0 + 1 < ADIM) x1 = ap[k0 + 1];
        if (k0 + 2 < ADIM) x2 = ap[k0 + 2];
        if (k0 + 3 < ADIM) x3 = ap[k0 + 3];
      }
      half4 hv = {(_Float16)x0, (_Float16)x1, (_Float16)x2, (_Float16)x3};
      int off = r * 64 + ((c4 * 8) ^ ((r & 3) << 4));
      *(half4*)(Ab + off) = hv;
    }
    // B: 128 rows x 32 f16 via gload_lds (8 chunks of 1KB)
    #pragma unroll
    for (int q = 0; q < 2; ++q) {
      int ci = wid * 2 + q;
      int r = ci * 16 + (lane >> 2);
      int slot = (lane & 3) ^ (r & 3);
      gload16(B + (size_t)(col0 + r) * KPAD_IN + kb + slot * 8, Bb + ci * 1024);
    }
    __syncthreads();
    half8 af[4], bf[4];
    #pragma unroll
    for (int i = 0; i < 4; ++i) {
      int r = wm * 64 + i * 16 + (lane & 15);
      int slot = (lane >> 4) ^ (r & 3);
      af[i] = *(const half8*)(Ab + r * 64 + slot * 16);
    }
    #pragma unroll
    for (int j = 0; j < 4; ++j) {
      int r = wn * 64 + j * 16 + (lane & 15);
      int slot = (lane >> 4) ^ (r & 3);
      bf[j] = *(const half8*)(Bb + r * 64 + slot * 16);
    }
    #pragma unroll
    for (int i = 0; i < 4; ++i)
      #pragma unroll
      for (int j = 0; j < 4; ++j)
        acc[i][j] = __builtin_amdgcn_mfma_f32_16x16x32_f16(af[i], bf[j], acc[i][j], 0, 0, 0);
    __syncthreads();
  }
  gemm_epilogue(acc, smem, t, lane, wm, wn, row0, col0, M, bias0, bias0, outS, outS);
}

// ------------- fused edge phase: online segment-softmax + aggregate --------
// 2 nodes per wave (32 lanes/node, 8 dims/lane). Prefetched CSR gather,
// defer-max online softmax, no atomics.
__global__ __launch_bounds__(256)
void k_fused(const int* __restrict__ offs, const int* __restrict__ esrc,
             const _Float16* __restrict__ fs, const _Float16* __restrict__ fd,
             const float* __restrict__ attn, const float* __restrict__ bias,
             _Float16* __restrict__ hhalf, float* __restrict__ hfloat, int N)
{
  int n = blockIdx.x * 8 + (threadIdx.x >> 5);
  if (n >= N) return;
  int sub = threadIdx.x & 31;
  int h = sub >> 3;
  int j0 = sub * 8;
  half8 fdv = *(const half8*)&fd[(size_t)n * HID + j0];
  float4 av0 = *(const float4*)&attn[h * DOUT + (sub & 7) * 8];
  float4 av1 = *(const float4*)&attn[h * DOUT + (sub & 7) * 8 + 4];
  float fdf[8], avf[8];
  #pragma unroll
  for (int q = 0; q < 4; ++q) { avf[q] = ((const float*)&av0)[q]; avf[q + 4] = ((const float*)&av1)[q]; }
  #pragma unroll
  for (int q = 0; q < 8; ++q) fdf[q] = (float)fdv[q];

  int t0 = offs[n], t1 = offs[n + 1];
  float m = -1e30f, ssum = 0.f;
  float a[8];
  #pragma unroll
  for (int q = 0; q < 8; ++q) a[q] = 0.f;

  half8 fN = {};
  if (t0 < t1) {
    int s0 = esrc[t0];
    fN = *(const half8*)&fs[(size_t)s0 * HID + j0];
  }
  for (int tt = t0; tt < t1; ++tt) {
    half8 fv = fN;
    if (tt + 1 < t1) {
      int s2 = esrc[tt + 1];
      fN = *(const half8*)&fs[(size_t)s2 * HID + j0];
    }
    float f[8];
    #pragma unroll
    for (int q = 0; q < 8; ++q) f[q] = (float)fv[q];
    float p = 0.f;
    #pragma unroll
    for (int q = 0; q < 8; ++q) {
      float x = f[q] + fdf[q];
      x = x > 0.f ? x : 0.2f * x;
      p += x * avf[q];
    }
    p += __shfl_xor(p, 1);
    p += __shfl_xor(p, 2);
    p += __shfl_xor(p, 4);     // 8-lane head group holds the logit
    if (p > m) {
      float sc = __expf(m - p);
      ssum = ssum * sc + 1.f;
      #pragma unroll
      for (int q = 0; q < 8; ++q) a[q] = a[q] * sc + f[q];
      m = p;
    } else {
      float w = __expf(p - m);
      ssum += w;
      #pragma unroll
      for (int q = 0; q < 8; ++q) a[q] += w * f[q];
    }
  }
  float inv = (t1 > t0) ? 1.0f / ssum : 0.f;
  float o[8];
  #pragma unroll
  for (int q = 0; q < 8; ++q) o[q] = a[q] * inv + bias[j0 + q];
  if (hhalf) {
    half8 hv;
    #pragma unroll
    for (int q = 0; q < 8; ++q) hv[q] = (_Float16)o[q];
    *(half8*)&hhalf[(size_t)n * HID + j0] = hv;
  }
  if (hfloat) {
    float4 v0 = {o[0], o[1], o[2], o[3]};
    float4 v1 = {o[4], o[5], o[6], o[7]};
    *(float4*)&hfloat[(size_t)n * HID + j0] = v0;
    *(float4*)&hfloat[(size_t)n * HID + j0 + 4] = v1;
  }
}

// ---------------- CSR build ------------------------------------------------
__global__ void k_zero_i(int* p, int n) {
  int i = blockIdx.x * 256 + threadIdx.x;
  if (i < n) p[i] = 0;
}
__global__ void k_count(const int* __restrict__ dst, int* __restrict__ counts, int E) {
  int i = blockIdx.x * 256 + threadIdx.x;
  if (i < E) atomicAdd(&counts[dst[i]], 1);
}
__global__ __launch_bounds__(1024)
void k_scan1(const int* __restrict__ counts, int* __restrict__ offs,
             int* __restrict__ bsums, int N)
{
  __shared__ int sd[1024];
  int t = threadIdx.x, i = blockIdx.x * 1024 + t;
  int x = (i < N) ? counts[i] : 0;
  sd[t] = x;
  __syncthreads();
  for (int off = 1; off < 1024; off <<= 1) {
    int v = (t >= off) ? sd[t - off] : 0;
    __syncthreads();
    sd[t] += v;
    __syncthreads();
  }
  if (i < N) offs[i] = sd[t] - x;
  if (t == 0) bsums[blockIdx.x] = sd[1023];
}
__global__ void k_scan2(const int* __restrict__ bsums, int* __restrict__ boffs,
                        int* __restrict__ offs, int nb, int N)
{
  if (threadIdx.x == 0 && blockIdx.x == 0) {
    int run = 0;
    for (int b = 0; b < nb; ++b) { boffs[b] = run; run += bsums[b]; }
    offs[N] = run;
  }
}
__global__ __launch_bounds__(1024)
void k_scan3(const int* __restrict__ boffs, int* __restrict__ offs,
             int* __restrict__ cursor, int N)
{
  int i = blockIdx.x * 1024 + threadIdx.x;
  if (i < N) {
    int v = offs[i] + boffs[blockIdx.x];
    offs[i] = v;
    cursor[i] = v;
  }
}
__global__ void k_scatter(const int* __restrict__ src, const int* __restrict__ dst,
                          int* __restrict__ cursor, int* __restrict__ esrc, int E)
{
  int i = blockIdx.x * 256 + threadIdx.x;
  if (i < E) {
    int pos = atomicAdd(&cursor[dst[i]], 1);
    esrc[pos] = src[i];
  }
}

// ---------------- launch ---------------------------------------------------
extern "C" void kernel_launch(void* const* d_in, const int* in_sizes, int n_in,
                              void* d_out, int out_size, void* d_ws, size_t ws_size,
                              hipStream_t stream)
{
  const float* atom  = (const float*)d_in[0];
  const int*   src   = (const int*)d_in[1];
  const int*   dst   = (const int*)d_in[2];
  const float* W_in  = (const float*)d_in[3];
  const float* b_in  = (const float*)d_in[4];
  const float* W_src = (const float*)d_in[5];
  const float* b_src = (const float*)d_in[6];
  const float* W_dst = (const float*)d_in[7];
  const float* b_dst = (const float*)d_in[8];
  const float* attn  = (const float*)d_in[9];
  const float* bias  = (const float*)d_in[10];

  const int N = in_sizes[0] / ADIM;
  const int E = in_sizes[1];
  _Float16* h_half = (_Float16*)d_out;
  float*    h_out  = (float*)d_out;

  char* w = (char*)d_ws;
  size_t off = 0;
  auto carve = [&](size_t bytes) {
    void* p = w + off;
    off = (off + bytes + 255) & ~(size_t)255;
    return p;
  };
  _Float16* fs    = (_Float16*)carve((size_t)N * HID * 2);
  _Float16* fd    = (_Float16*)carve((size_t)N * HID * 2);
  _Float16* WT    = (_Float16*)carve((size_t)512 * HID * 2);
  _Float16* WTin  = (_Float16*)carve((size_t)HID * KPAD_IN * 2);
  int*      counts= (int*)carve((size_t)N * 4);
  int*      offs  = (int*)carve((size_t)(N + 1) * 4);
  int*      cursor= (int*)carve((size_t)N * 4);
  int*      esrc  = (int*)carve((size_t)E * 4);
  int*      bsums = (int*)carve((size_t)1024 * 4);
  int*      boffs = (int*)carve((size_t)1024 * 4);
  (void)ws_size; (void)n_in; (void)out_size;

  const int nb = (N + 1023) / 1024;
  const int gmx = (N + 127) / 128;

  // CSR by dst (layer-invariant)
  k_zero_i<<<(N + 255) / 256, 256, 0, stream>>>(counts, N);
  k_count<<<(E + 255) / 256, 256, 0, stream>>>(dst, counts, E);
  k_scan1<<<nb, 1024, 0, stream>>>(counts, offs, bsums, N);
  k_scan2<<<1, 64, 0, stream>>>(bsums, boffs, offs, nb, N);
  k_scan3<<<nb, 1024, 0, stream>>>(boffs, offs, cursor, N);
  k_scatter<<<(E + 255) / 256, 256, 0, stream>>>(src, dst, cursor, esrc, E);

  // input projection -> h_half (f16)
  k_prep_win<<<(HID * KPAD_IN + 255) / 256, 256, 0, stream>>>(W_in, WTin);
  k_gemm_f<<<dim3(2, gmx), 256, 0, stream>>>(atom, N, WTin, b_in, h_half);

  for (int l = 0; l < LAYERS; ++l) {
    k_prep_wt<<<(512 * HID + 255) / 256, 256, 0, stream>>>(W_src + (size_t)l * HID * HID,
                                                           W_dst + (size_t)l * HID * HID, WT);
    k_gemm_h<<<dim3(4, gmx), 256, 0, stream>>>(h_half, N, WT,
                                               b_src + (size_t)l * HID,
                                               b_dst + (size_t)l * HID, fs, fd);
    const bool last = (l == LAYERS - 1);
    k_fused<<<(N + 7) / 8, 256, 0, stream>>>(offs, esrc, fs, fd,
                                             attn + (size_t)l * NHEAD * DOUT,
                                             bias + (size_t)l * HID,
                                             last ? nullptr : h_half,
                                             last ? h_out : nullptr, N);
  }
}